// Round 10
// baseline (20062.791 us; speedup 1.0000x reference)
//
#include <hip/hip_runtime.h>
#include <math.h>

#define Gz   500
#define NTz  512
#define Bz   32
#define Hz   512
#define Vz   32000
#define Tz   128
#define VBz  64        // vocab rows per block (500*64 = 32000)
#define NLB  256       // LSTM blocks (2 hidden units each)
#define BHz  (Bz*Hz)
#define LBHz (2*BHz)
#define BTVz ((size_t)Bz*(size_t)Tz*(size_t)Vz)

// workspace byte offsets
#define WS_BAR  0        // unsigned: grp[i] at [i*32] (16 groups), master [512], gen [513]
#define WS_ASUM 4096     // float[128][32]
#define WS_AMAX 20480    // ull[128][32]
#define WS_H    53248    // float[2 parity][2 layer][32][512]

// LDS byte offsets (dynamic) -- total 75648 <= 80KB -> 2 blocks/CU
#define L_HS    0        // float[32][512] swizzled (P3 tile)
#define L_PMAX  65536    // ull[16][32]
#define L_PSUM  69632    // float[16][32]
#define L_REDM  71680    // ull[8][32]
#define L_REDS  73728    // float[8][32]
#define L_LOGZ  74752    // float[32]
#define L_TOK   74880    // int[32]
#define L_BIAS  75008    // float[2][8]
#define L_C     75136    // float[2][2][32]
#define L_TOTAL 75648

typedef unsigned long long ull;
typedef float f32x4 __attribute__((ext_vector_type(4)));
typedef float f32x2 __attribute__((ext_vector_type(2)));

__device__ __forceinline__ float sigmf(float x) { return 1.0f / (1.0f + expf(-x)); }

__device__ __forceinline__ ull bp8(const float* p) {   // coherent 8B load (MALL-direct)
  return __hip_atomic_load((const ull*)p, __ATOMIC_RELAXED, __HIP_MEMORY_SCOPE_AGENT);
}
__device__ __forceinline__ f32x2 bp8f(const float* p) {
  ull v = bp8(p);
  f32x2 r;
  r.x = __uint_as_float((unsigned)(v & 0xFFFFFFFFull));
  r.y = __uint_as_float((unsigned)(v >> 32));
  return r;
}
__device__ __forceinline__ void cstore(float* p, float v) {  // MALL-direct 4B store
  __hip_atomic_store(p, v, __ATOMIC_RELAXED, __HIP_MEMORY_SCOPE_AGENT);
}
__device__ __forceinline__ ull packlm(float x, int v) {
  unsigned u = __float_as_uint(x);
  u = (u & 0x80000000u) ? ~u : (u | 0x80000000u);
  return ((ull)u << 32) | (unsigned)(Vz - 1 - v);   // lower v wins ties (np.argmax first-max)
}
__device__ __forceinline__ int hoff(int b, int k) { return (b << 9) + (k ^ ((b & 15) << 2)); }

// ALL-RELAXED grid barrier (R7/R8-proven), 16 groups for Gz=500.
__device__ __forceinline__ void grid_barrier(unsigned* bar, int bid) {
  __syncthreads();
  if (threadIdx.x == 0) {
    unsigned* gen = bar + 513;
    unsigned g = __hip_atomic_load(gen, __ATOMIC_RELAXED, __HIP_MEMORY_SCOPE_AGENT);
    const int gi = bid & 15;
    const unsigned gsz = (unsigned)(Gz >> 4) + (((unsigned)gi < (Gz & 15u)) ? 1u : 0u);
    unsigned prev = __hip_atomic_fetch_add(&bar[gi * 32], 1u, __ATOMIC_RELAXED, __HIP_MEMORY_SCOPE_AGENT);
    if (prev == gsz - 1u) {
      __hip_atomic_store(&bar[gi * 32], 0u, __ATOMIC_RELAXED, __HIP_MEMORY_SCOPE_AGENT);
      asm volatile("s_waitcnt vmcnt(0)" ::: "memory");
      unsigned pm = __hip_atomic_fetch_add(&bar[512], 1u, __ATOMIC_RELAXED, __HIP_MEMORY_SCOPE_AGENT);
      if (pm == 15u) {
        __hip_atomic_store(&bar[512], 0u, __ATOMIC_RELAXED, __HIP_MEMORY_SCOPE_AGENT);
        asm volatile("s_waitcnt vmcnt(0)" ::: "memory");
        __hip_atomic_store(gen, g + 1u, __ATOMIC_RELAXED, __HIP_MEMORY_SCOPE_AGENT);
      }
    }
    while (__hip_atomic_load(gen, __ATOMIC_RELAXED, __HIP_MEMORY_SCOPE_AGENT) == g)
      __builtin_amdgcn_s_sleep(1);
  }
  __syncthreads();
}

// stage [32][512] floats from coherent global into swizzled LDS tile (coalesced)
__device__ __forceinline__ void stage_rows(const float* __restrict__ src, float* lds, int tid) {
  #pragma unroll
  for (int it = 0; it < 16; ++it) {
    int f = (it * NTz + tid) << 1;
    int b = f >> 9, k = f & 511;
    ull v = bp8(src + f);
    *(ull*)(lds + hoff(b, k)) = v;
  }
}

// Tile-less LSTM layer. 512 threads = 32 b x 16 kq. Thread (b,kq) handles this
// block's 8 gate-rows over interleaved k slice {kq*2 + 32j : j<16}; x/h read as
// coalesced coherent 8B loads (16-lane groups contiguous); 4-round shfl_xor
// reduce; kq==0 lane does the cell update for both hidden units.
template<bool X_FROM_EMB>
__device__ __forceinline__ void lstm_tl(
    int tid, int hblk, int layer,
    const float* __restrict__ emb, const int* s_tok_,
    const float* __restrict__ xsrc,   // !X_FROM_EMB: [32][512] coherent
    const float* __restrict__ hsrc,   // [32][512] coherent
    const float* __restrict__ Wl_ih, const float* __restrict__ Wl_hh,  // layer bases
    const float* s_bias_,             // [8] this layer
    float* c_l,                       // [2][32] this layer
    float* __restrict__ hdst)         // [32][512]
{
  const int b = tid >> 4, kq = tid & 15;
  const int k0 = kq << 1;

  const float* xrow;
  if (X_FROM_EMB) xrow = emb + (size_t)s_tok_[b] * Hz;
  else            xrow = xsrc + (b << 9);
  const float* hrow = hsrc + (b << 9);

  const float* wi[8]; const float* wh[8];
  #pragma unroll
  for (int r = 0; r < 8; ++r) {
    // row r = gate*2 + u  (gate = r>>1, u = r&1)
    int j = (r >> 1) * Hz + (hblk << 1) + (r & 1);
    wi[r] = Wl_ih + (size_t)j * Hz;
    wh[r] = Wl_hh + (size_t)j * Hz;
  }

  float acc[8];
  #pragma unroll
  for (int r = 0; r < 8; ++r) acc[r] = 0.f;

  #pragma unroll 4
  for (int j = 0; j < 16; ++j) {
    const int k = k0 + (j << 5);
    f32x2 xv;
    if (X_FROM_EMB) {
      f32x2 e = *(const f32x2*)(xrow + k);       // read-only, normal cached
      xv.x = fmaxf(e.x, 0.f); xv.y = fmaxf(e.y, 0.f);
    } else {
      xv = bp8f(xrow + k);                        // coherent (other blocks wrote)
    }
    f32x2 hv = bp8f(hrow + k);
    #pragma unroll
    for (int r = 0; r < 8; ++r) {
      f32x2 wiv = *(const f32x2*)(wi[r] + k);     // weights: normal cached
      f32x2 whv = *(const f32x2*)(wh[r] + k);
      acc[r] += xv.x * wiv.x + xv.y * wiv.y + hv.x * whv.x + hv.y * whv.y;
    }
  }
  // reduce over 16 kq lanes (contiguous lane groups; xor masks stay in-group)
  #pragma unroll
  for (int r = 0; r < 8; ++r) {
    float a = acc[r];
    a += __shfl_xor(a, 8);
    a += __shfl_xor(a, 4);
    a += __shfl_xor(a, 2);
    a += __shfl_xor(a, 1);
    acc[r] = a;
  }
  if (kq == 0) {
    #pragma unroll
    for (int u = 0; u < 2; ++u) {
      float gi = acc[0 + u] + s_bias_[0 + u];
      float gf = acc[2 + u] + s_bias_[2 + u];
      float gg = acc[4 + u] + s_bias_[4 + u];
      float go = acc[6 + u] + s_bias_[6 + u];
      float c_old = c_l[u * 32 + b];
      float cn = sigmf(gf) * c_old + sigmf(gi) * tanhf(gg);
      c_l[u * 32 + b] = cn;
      cstore(hdst + (b << 9) + (hblk << 1) + u, sigmf(go) * tanhf(cn));
    }
  }
}

__device__ __forceinline__ void tok_reduce(int tid, float* acc_sum, ull* acc_max,
                                           float* redS, ull* redM, float* logZ, int* tok) {
  if (tid < 256) {
    int b = tid & 31, g = tid >> 5;
    float s = 0.f; ull m = 0ull;
    #pragma unroll
    for (int u = 0; u < 16; ++u) {
      int bk = g * 16 + u;
      s += __hip_atomic_load(&acc_sum[bk * Bz + b], __ATOMIC_RELAXED, __HIP_MEMORY_SCOPE_AGENT);
      ull x = __hip_atomic_load(&acc_max[bk * Bz + b], __ATOMIC_RELAXED, __HIP_MEMORY_SCOPE_AGENT);
      m = x > m ? x : m;
    }
    redS[g * Bz + b] = s; redM[g * Bz + b] = m;
  }
  __syncthreads();
  if (tid < 32) {
    float s = 0.f; ull m = 0ull;
    #pragma unroll
    for (int g = 0; g < 8; ++g) {
      s += redS[g * Bz + tid];
      ull x = redM[g * Bz + tid]; m = x > m ? x : m;
    }
    logZ[tid] = logf(s);
    tok[tid] = (Vz - 1) - (int)(unsigned)(m & 0xFFFFFFFFull);
  }
  __syncthreads();
}

__global__ void rnn_init(const float* __restrict__ enc, float* __restrict__ ws) {
  int i = blockIdx.x * blockDim.x + threadIdx.x;   // 32768 threads
  float* hs = (float*)((char*)ws + WS_H);
  if (i < LBHz) hs[i] = enc[i];
  if (i < 4096) {
    ((float*)((char*)ws + WS_ASUM))[i] = 0.f;
    ((ull*)((char*)ws + WS_AMAX))[i] = 0ull;
  }
  if (i < 1024) ((unsigned*)ws)[i] = 0u;
}

__global__ __launch_bounds__(NTz, 4) void rnn_decode(
    const float* __restrict__ emb,  const float* __restrict__ Wih,
    const float* __restrict__ Whh,  const float* __restrict__ bih,
    const float* __restrict__ bhh,  const float* __restrict__ Wout,
    const float* __restrict__ bout, float* __restrict__ out,
    float* __restrict__ ws)
{
  extern __shared__ char smem[];
  const int tid = threadIdx.x;
  const int bid = blockIdx.x;

  unsigned* bar  = (unsigned*)ws;
  float* acc_sum = (float*)((char*)ws + WS_ASUM);
  ull*   acc_max = (ull*)((char*)ws + WS_AMAX);
  float* hbufs   = (float*)((char*)ws + WS_H);

  float* HS     = (float*)(smem + L_HS);
  ull*   pmax   = (ull*)(smem + L_PMAX);
  float* psum   = (float*)(smem + L_PSUM);
  ull*   redM   = (ull*)(smem + L_REDM);
  float* redS   = (float*)(smem + L_REDS);
  float* s_logZ = (float*)(smem + L_LOGZ);
  int*   s_tok  = (int*)(smem + L_TOK);
  float* s_bias = (float*)(smem + L_BIAS);
  float* s_c    = (float*)(smem + L_C);

  const int v0 = bid * VBz;
  const int pb = tid & 31, prw = tid >> 5;   // P3/logp mapping: batch, row-quad

  if (tid < 128) s_c[tid] = 0.f;
  if (bid < NLB && tid < 16) {
    // bias for this block's 8 rows x 2 layers: row r = gate*2+u
    int l = tid >> 3, r = tid & 7;
    int j = l * 2048 + (r >> 1) * Hz + (bid << 1) + (r & 1);
    s_bias[tid] = bih[j] + bhh[j];
  }
  __syncthreads();

  float lg[4];   // this thread's 4 logits (rows v0+prw*4..+3, batch pb)

  for (int t = 0; t < Tz; ++t) {
    float* h_old = hbufs + (t & 1) * LBHz;
    float* h_new = hbufs + ((t + 1) & 1) * LBHz;

    //---- P1: token decode; logp(t-1) from registers; LSTM layer 0 ----
    if (t == 0) {
      if (tid < 32) s_tok[tid] = 1;   // SOS
      __syncthreads();
    } else {
      tok_reduce(tid, acc_sum, acc_max, redS, redM, s_logZ, s_tok);
      {
        float lz = s_logZ[pb];
        f32x4 rr; rr.x = lg[0] - lz; rr.y = lg[1] - lz; rr.z = lg[2] - lz; rr.w = lg[3] - lz;
        __builtin_nontemporal_store(rr,
            (f32x4*)(out + (size_t)pb * ((size_t)Tz * Vz) + (size_t)(t - 1) * Vz + v0 + (prw << 2)));
      }
    }
    if (bid < NLB)
      lstm_tl<true>(tid, bid, 0, emb, s_tok, nullptr, h_old,
                    Wih, Whh, s_bias, s_c, h_new);
    grid_barrier(bar, bid);

    //---- P2: LSTM layer 1 (x = fresh h0_new, h = h1_old); zero buckets ----
    if (bid < NLB)
      lstm_tl<false>(tid, bid, 1, nullptr, nullptr, h_new, h_old + BHz,
                     Wih + (size_t)2048 * Hz, Whh + (size_t)2048 * Hz,
                     s_bias + 8, s_c + 64, h_new + BHz);
    else if (bid == 300) {
      #pragma unroll
      for (int q = 0; q < 8; ++q) {
        int u = q * NTz + tid;
        __hip_atomic_store(&acc_sum[u], 0.f, __ATOMIC_RELAXED, __HIP_MEMORY_SCOPE_AGENT);
        __hip_atomic_store(&acc_max[u], 0ull, __ATOMIC_RELAXED, __HIP_MEMORY_SCOPE_AGENT);
      }
    }
    grid_barrier(bar, bid);

    //---- P3: stage h2 tile; 4-row scatter matvec; softmax partials ----
    stage_rows(h_new + BHz, HS, tid);
    __syncthreads();
    {
      const int swz = (pb & 15) << 2;
      const float* hb = HS + (pb << 9);
      const float* wbase = Wout + (size_t)(v0 + (prw << 2)) * Hz;
      float a0 = 0.f, a1 = 0.f, a2 = 0.f, a3 = 0.f;
      #pragma unroll 4
      for (int k = 0; k < Hz; k += 4) {
        f32x4 h4 = *(const f32x4*)(hb + (k ^ swz));
        f32x4 w0 = *(const f32x4*)(wbase + k);
        f32x4 w1 = *(const f32x4*)(wbase + Hz + k);
        f32x4 w2 = *(const f32x4*)(wbase + 2 * Hz + k);
        f32x4 w3 = *(const f32x4*)(wbase + 3 * Hz + k);
        a0 += h4.x * w0.x + h4.y * w0.y + h4.z * w0.z + h4.w * w0.w;
        a1 += h4.x * w1.x + h4.y * w1.y + h4.z * w1.z + h4.w * w1.w;
        a2 += h4.x * w2.x + h4.y * w2.y + h4.z * w2.z + h4.w * w2.w;
        a3 += h4.x * w3.x + h4.y * w3.y + h4.z * w3.z + h4.w * w3.w;
      }
      lg[0] = a0 + bout[v0 + (prw << 2)];
      lg[1] = a1 + bout[v0 + (prw << 2) + 1];
      lg[2] = a2 + bout[v0 + (prw << 2) + 2];
      lg[3] = a3 + bout[v0 + (prw << 2) + 3];
      // per-thread softmax partial over 4 logits (offset-0: logits O(1), safe)
      float m = lg[0]; int av = 0;
      if (lg[1] > m) { m = lg[1]; av = 1; }
      if (lg[2] > m) { m = lg[2]; av = 2; }
      if (lg[3] > m) { m = lg[3]; av = 3; }
      float s = expf(lg[0]) + expf(lg[1]) + expf(lg[2]) + expf(lg[3]);
      pmax[prw * 32 + pb] = packlm(m, v0 + (prw << 2) + av);
      psum[prw * 32 + pb] = s;
    }
    __syncthreads();
    if (tid < 32) {
      ull m = 0ull; float s = 0.f;
      #pragma unroll
      for (int ch = 0; ch < 16; ++ch) {
        ull x = pmax[ch * 32 + tid]; m = x > m ? x : m;
        s += psum[ch * 32 + tid];
      }
      atomicAdd(&acc_sum[(bid & 127) * Bz + tid], s);
      atomicMax(&acc_max[(bid & 127) * Bz + tid], m);
    }
    grid_barrier(bar, bid);
  }

  //---- epilogue: logp(T-1), hT, cT ----
  tok_reduce(tid, acc_sum, acc_max, redS, redM, s_logZ, s_tok);
  {
    float lz = s_logZ[pb];
    f32x4 rr; rr.x = lg[0] - lz; rr.y = lg[1] - lz; rr.z = lg[2] - lz; rr.w = lg[3] - lz;
    __builtin_nontemporal_store(rr,
        (f32x4*)(out + (size_t)pb * ((size_t)Tz * Vz) + (size_t)(Tz - 1) * Vz + v0 + (prw << 2)));
  }
  if (bid >= NLB && bid < NLB + 32) {
    int f = (bid - NLB) * 1024 + tid * 2;   // hT: 32768 floats from parity-0 buffer
    *(ull*)(out + BTVz + f) = bp8(hbufs + f);
  }
  if (bid < NLB && tid < 128) {
    int l = tid >> 6, u = (tid >> 5) & 1, b = tid & 31;
    out[BTVz + LBHz + (size_t)l * BHz + (size_t)b * Hz + (bid << 1) + u] =
        s_c[l * 64 + u * 32 + b];
  }
}

extern "C" void kernel_launch(void* const* d_in, const int* in_sizes, int n_in,
                              void* d_out, int out_size, void* d_ws, size_t ws_size,
                              hipStream_t stream) {
  (void)in_sizes; (void)n_in; (void)out_size; (void)ws_size;
  const float* enc  = (const float*)d_in[0];
  const float* emb  = (const float*)d_in[1];
  const float* Wih  = (const float*)d_in[2];
  const float* Whh  = (const float*)d_in[3];
  const float* bih  = (const float*)d_in[4];
  const float* bhh  = (const float*)d_in[5];
  const float* Wout = (const float*)d_in[6];
  const float* bout = (const float*)d_in[7];
  float* out = (float*)d_out;
  float* ws  = (float*)d_ws;

  (void)hipFuncSetAttribute((const void*)rnn_decode,
                            hipFuncAttributeMaxDynamicSharedMemorySize, L_TOTAL);
  rnn_init<<<64, 512, 0, stream>>>(enc, ws);
  rnn_decode<<<Gz, NTz, L_TOTAL, stream>>>(emb, Wih, Whh, bih, bhh, Wout, bout, out, ws);
}